// Round 11
// baseline (158.997 us; speedup 1.0000x reference)
//
#include <hip/hip_runtime.h>
#include <hip/hip_bf16.h>

#define NCLS 200
#define NPADP 224       // logical proto rows = 14 x 16
#define NROWS 256       // padded rows in protoI image
#define NTW 7           // class tiles per wave (2 N-waves x 7 x 16 = 224)
#define DIM 512
#define NSAMP 32768
#define NSEG 8          // psum sample segments
#define CAP 32          // per-wave list capacity
#define BM 64           // sample rows per block
#define BK 32           // k per chunk
#define KIT 16          // DIM / BK
#define CHUS (NROWS*32) // ushorts per chunk image (8192)
#define NB1 (NSEG*NCLS) // K1 grid = 1600
#define NB2 512         // K2 grid

typedef __attribute__((ext_vector_type(4))) float f32x4;
typedef __attribute__((ext_vector_type(4))) int   i32x4;
typedef __attribute__((ext_vector_type(8))) short bf16x8;

__device__ inline short bf16s(float x) {
  __hip_bfloat16 h = __float2bfloat16(x);
  return *reinterpret_cast<short*>(&h);
}

__device__ inline bf16x8 pack8(f32x4 a, f32x4 b) {
  bf16x8 r;
  r[0] = bf16s(a[0]); r[1] = bf16s(a[1]); r[2] = bf16s(a[2]); r[3] = bf16s(a[3]);
  r[4] = bf16s(b[0]); r[5] = bf16s(b[1]); r[6] = bf16s(b[2]); r[7] = bf16s(b[3]);
  return r;
}

__device__ inline float sumsq(f32x4 a) {
  return a[0]*a[0] + a[1]*a[1] + a[2]*a[2] + a[3]*a[3];
}

// ---------------- Kernel 1: psum (all blocks) + pcomb (last-224 ticket tail) ---
// 1600 blocks x 512 thr. Each block: per-(class,segment) partial sum (R10 psum).
// Tickets 1376..1599 spin until all 1600 done, then each combines one class ->
// swizzled chunk-major bf16 protoI + p2. Deterministic: result independent of
// which block executes which class.
__global__ __launch_bounds__(512) void k_proto(
    const float* __restrict__ feat, const int* __restrict__ labels,
    float* __restrict__ psum, int* __restrict__ pcnt,
    unsigned short* __restrict__ protoI, float* __restrict__ p2out,
    unsigned int* __restrict__ cnt1)
{
  const int bx = blockIdx.x;
  const int c = bx >> 3, s = bx & 7;
  const int tid = threadIdx.x;
  const int lane = tid & 63;
  const int w = tid >> 6;

  __shared__ int   lists[8][CAP];
  __shared__ int   cnts[8];
  __shared__ float partial[8][DIM];
  __shared__ unsigned int tsh;

  int cnt = 0;
  const int segbase = s * (NSAMP / NSEG) + w * (NSAMP / NSEG / 8);
  #pragma unroll
  for (int i = 0; i < 2; ++i) {
    const int base = segbase + i * 256 + lane * 4;
    const i32x4 lab4 = *(const i32x4*)(labels + base);
    #pragma unroll
    for (int u = 0; u < 4; ++u) {
      const bool m = (lab4[u] == c);
      const unsigned long long bal = __ballot(m);
      if (m) {
        const int pos = cnt + __popcll(bal & ((1ull << lane) - 1ull));
        if (pos < CAP) lists[w][pos] = base + u;
      }
      cnt += __popcll(bal);
    }
  }
  if (cnt > CAP) cnt = CAP;
  if (lane == 0) cnts[w] = cnt;

  float aE[8], aO[8];
  #pragma unroll
  for (int q = 0; q < 8; ++q) { aE[q] = 0.f; aO[q] = 0.f; }
  int j = 0;
  for (; j + 2 <= cnt; j += 2) {
    const int r0 = lists[w][j], r1 = lists[w][j + 1];
    const f32x4 a0 = *(const f32x4*)(feat + (size_t)r0 * DIM + lane * 8);
    const f32x4 b0 = *(const f32x4*)(feat + (size_t)r0 * DIM + lane * 8 + 4);
    const f32x4 a1 = *(const f32x4*)(feat + (size_t)r1 * DIM + lane * 8);
    const f32x4 b1 = *(const f32x4*)(feat + (size_t)r1 * DIM + lane * 8 + 4);
    aE[0] += a0[0]; aE[1] += a0[1]; aE[2] += a0[2]; aE[3] += a0[3];
    aE[4] += b0[0]; aE[5] += b0[1]; aE[6] += b0[2]; aE[7] += b0[3];
    aO[0] += a1[0]; aO[1] += a1[1]; aO[2] += a1[2]; aO[3] += a1[3];
    aO[4] += b1[0]; aO[5] += b1[1]; aO[6] += b1[2]; aO[7] += b1[3];
  }
  if (j < cnt) {
    const int r0 = lists[w][j];
    const f32x4 a0 = *(const f32x4*)(feat + (size_t)r0 * DIM + lane * 8);
    const f32x4 b0 = *(const f32x4*)(feat + (size_t)r0 * DIM + lane * 8 + 4);
    aE[0] += a0[0]; aE[1] += a0[1]; aE[2] += a0[2]; aE[3] += a0[3];
    aE[4] += b0[0]; aE[5] += b0[1]; aE[6] += b0[2]; aE[7] += b0[3];
  }
  #pragma unroll
  for (int q = 0; q < 8; ++q) partial[w][lane * 8 + q] = aE[q] + aO[q];
  __syncthreads();

  int total = 0;
  #pragma unroll
  for (int u = 0; u < 8; ++u) total += cnts[u];
  float sv = 0.f;
  #pragma unroll
  for (int u = 0; u < 8; ++u) sv += partial[u][tid];
  psum[(size_t)(s * NCLS + c) * DIM + tid] = sv;
  if (tid == 0) pcnt[s * NCLS + c] = total;

  // ---- ticket: release psum stores, take a number ----
  __syncthreads();
  if (tid == 0) {
    __threadfence();
    tsh = atomicAdd(cnt1, 1u);
  }
  __syncthreads();
  const unsigned int ticket = tsh;
  if (ticket < (unsigned)(NB1 - NPADP)) return;
  const int cc = (int)(ticket - (unsigned)(NB1 - NPADP));   // 0..223

  // ---- wait for all psum blocks, acquire ----
  if (tid == 0) {
    while (atomicAdd(cnt1, 0u) < (unsigned)NB1) __builtin_amdgcn_s_sleep(8);
  }
  __syncthreads();
  __threadfence();

  // ---- pcomb for class cc (512 threads, thread = dim) ----
  const int sw = (cc >> 1) & 3;
  const int d = tid;
  const int ck = d >> 5, uL = (d >> 3) & 3, e = d & 7;
  if (cc >= NCLS) {
    protoI[(size_t)ck * CHUS + cc * 32 + (uL ^ sw) * 8 + e] = 0;  // bf16 +0.0
    if (tid == 0) p2out[cc] = 1e30f;   // never wins argmin
    return;
  }
  float a = 0.f;
  int tot = 0;
  #pragma unroll
  for (int q = 0; q < NSEG; ++q) {     // fixed combine order: deterministic
    a += psum[(size_t)(q * NCLS + cc) * DIM + d];
    tot += pcnt[q * NCLS + cc];
  }
  const float p = a / ((float)tot + 1e-8f);   // counts + EPS
  protoI[(size_t)ck * CHUS + cc * 32 + (uL ^ sw) * 8 + e] = (unsigned short)bf16s(p);

  float* red = &partial[0][0];
  red[tid] = p * p;
  __syncthreads();
  for (int st = 256; st > 0; st >>= 1) {
    if (tid < st) red[tid] += red[tid + st];
    __syncthreads();
  }
  if (tid == 0) p2out[cc] = red[0];
}

// ---------------- Kernel 2: gload_lds-B MFMA GEMM + argmin + loss + finish -----
// R10's proven k_score, verbatim, plus a last-ticket tail that reduces the 512
// per-block partials and writes the scalar output (removes the finish launch).
__global__ __launch_bounds__(256) void k_score(
    const float* __restrict__ feat, const int* __restrict__ labels,
    const unsigned short* __restrict__ protoI, const float* __restrict__ p2,
    float* __restrict__ partials, float* __restrict__ out,
    unsigned int* __restrict__ cnt2)
{
  __shared__ __align__(16) unsigned short As[2][BM * BK];    // 8 KiB
  __shared__ __align__(1024) unsigned short Bs[2][CHUS];     // 32 KiB
  __shared__ float f2s[BM][4];
  __shared__ float rd_d[2][BM];
  __shared__ int   rd_c[2][BM];
  __shared__ float rd_p[2][BM];
  __shared__ unsigned int tsh;

  const int tid = threadIdx.x;
  const int lane = tid & 63;
  const int w = tid >> 6;
  const int wm = w >> 1, wn = w & 1;
  const int lr = lane & 15;
  const int kg = lane >> 4;
  const int blockRow = blockIdx.x * BM;

  // A staging: 4 threads/row, 8 floats each; XOR-swizzled 16B units
  const int arow = tid >> 2, apart = tid & 3;
  const float* agp = feat + (size_t)(blockRow + arow) * DIM + apart * 8;
  const int aoff = arow * BK + ((apart ^ (arow & 3)) * 8);

  float f2part = 0.f;

  f32x4 acc0[NTW], acc1[NTW];
  #pragma unroll
  for (int n = 0; n < NTW; ++n) {
    acc0[n] = f32x4{0.f, 0.f, 0.f, 0.f};
    acc1[n] = f32x4{0.f, 0.f, 0.f, 0.f};
  }

  const int r0v = wm * 32 + lr;
  const int r1v = r0v + 16;
  const int ar0 = r0v * BK + ((kg ^ (r0v & 3)) * 8);
  const int ar1 = r1v * BK + ((kg ^ (r1v & 3)) * 8);

#define ISSUE_A(T, S) do {                                                      \
    const float* ag_ = agp + (T) * BK;                                          \
    S##0 = *(const f32x4*)(ag_);                                                \
    S##1 = *(const f32x4*)(ag_ + 4);                                            \
  } while (0)

#define STOREA(NB, S) do {                                                      \
    f2part += sumsq(S##0) + sumsq(S##1);                                        \
    *(bf16x8*)&As[NB][aoff] = pack8(S##0, S##1);                                \
  } while (0)

#define BGLD(T, NB) do {                                                        \
    _Pragma("unroll")                                                           \
    for (int i_ = 0; i_ < 4; ++i_) {                                            \
      const int j_ = w * 4 + i_;                                                \
      const unsigned short* g_ = protoI + (size_t)(T) * CHUS + j_ * 512 + lane * 8; \
      unsigned short* l_ = &Bs[NB][j_ * 512];                                   \
      __builtin_amdgcn_global_load_lds(                                         \
          (const __attribute__((address_space(1))) void*)g_,                    \
          (__attribute__((address_space(3))) void*)l_, 16, 0, 0);               \
    }                                                                           \
  } while (0)

#define COMPUTE(CUR) do {                                                       \
    const bf16x8 Af0 = *(const bf16x8*)&As[CUR][ar0];                           \
    const bf16x8 Af1 = *(const bf16x8*)&As[CUR][ar1];                           \
    _Pragma("unroll")                                                           \
    for (int n = 0; n < NTW; ++n) {                                             \
      const int row_ = wn * 112 + n * 16 + lr;                                  \
      const bf16x8 Bf = *(const bf16x8*)&Bs[CUR][row_ * 32 + ((kg ^ ((row_ >> 1) & 3)) * 8)]; \
      acc0[n] = __builtin_amdgcn_mfma_f32_16x16x32_bf16(Af0, Bf, acc0[n], 0, 0, 0); \
      acc1[n] = __builtin_amdgcn_mfma_f32_16x16x32_bf16(Af1, Bf, acc1[n], 0, 0, 0); \
    }                                                                           \
  } while (0)

#define BAR_VM2() do {                                                          \
    asm volatile("s_waitcnt vmcnt(2)" ::: "memory");                            \
    asm volatile("s_waitcnt lgkmcnt(0)" ::: "memory");                          \
    __builtin_amdgcn_s_barrier();                                               \
  } while (0)

#define BAR_VM0() do {                                                          \
    asm volatile("s_waitcnt vmcnt(0)" ::: "memory");                            \
    asm volatile("s_waitcnt lgkmcnt(0)" ::: "memory");                          \
    __builtin_amdgcn_s_barrier();                                               \
  } while (0)

  f32x4 AE_0, AE_1;   // even-chunk A regs
  f32x4 AO_0, AO_1;   // odd-chunk A regs

  // ---- prologue ----
  ISSUE_A(0, AE_);
  BGLD(0, 0);
  __builtin_amdgcn_sched_barrier(0);
  ISSUE_A(1, AO_);
  STOREA(0, AE_);                 // auto-waits AE loads (drains BGLD0 too: ok)
  BAR_VM2();                      // keep AO in flight

  // ---- 16 chunk phases ----
  #pragma unroll
  for (int t = 0; t < KIT; ++t) {
    const int cur = t & 1;
    const int nxt = cur ^ 1;
    if (t + 1 < KIT) {
      if ((t & 1) == 0) STOREA(nxt, AO_); else STOREA(nxt, AE_);
      BGLD(t + 1, nxt);
      __builtin_amdgcn_sched_barrier(0);
    }
    if (t + 2 < KIT) {
      if ((t & 1) == 0) ISSUE_A(t + 2, AE_); else ISSUE_A(t + 2, AO_);
    }
    COMPUTE(cur);
    if (t + 1 < KIT) {
      if (t + 2 < KIT) BAR_VM2(); else BAR_VM0();
    }
  }
#undef ISSUE_A
#undef STOREA
#undef BGLD
#undef COMPUTE
#undef BAR_VM2
#undef BAR_VM0

  // exact per-row-part f2 (fixed combine order)
  f2s[arow][apart] = f2part;
  __syncthreads();

  float p2v[NTW];
  #pragma unroll
  for (int n = 0; n < NTW; ++n) p2v[n] = p2[wn * 112 + n * 16 + lr];

  #pragma unroll
  for (int m = 0; m < 2; ++m) {
    #pragma unroll
    for (int r = 0; r < 4; ++r) {
      const int srow = kg * 4 + r;                    // C/D row within 16-tile
      const int lrow = wm * 32 + m * 16 + srow;       // block-local sample row
      const float f2v = (f2s[lrow][0] + f2s[lrow][1]) + (f2s[lrow][2] + f2s[lrow][3]);
      const int lab = labels[blockRow + lrow];
      float bestd = 1e38f; int bestc = 1 << 30;
      float posd = -1.f;
      #pragma unroll
      for (int n = 0; n < NTW; ++n) {
        const int cidx = wn * 112 + n * 16 + lr;      // C/D col = class
        const float sc = (m == 0) ? acc0[n][r] : acc1[n][r];
        const float d2 = fmaxf(f2v + p2v[n] - 2.0f * sc, 0.0f);
        if (cidx == lab) posd = d2;
        else if (cidx < NCLS &&
                 (d2 < bestd || (d2 == bestd && cidx < bestc))) { bestd = d2; bestc = cidx; }
      }
      #pragma unroll
      for (int sft = 1; sft < 16; sft <<= 1) {        // 16-lane group reduce
        const float od = __shfl_xor(bestd, sft);
        const int   oc = __shfl_xor(bestc, sft);
        const float op = __shfl_xor(posd, sft);
        if (od < bestd || (od == bestd && oc < bestc)) { bestd = od; bestc = oc; }
        posd = fmaxf(posd, op);
      }
      if (lr == 0) {
        rd_d[wn][lrow] = bestd; rd_c[wn][lrow] = bestc; rd_p[wn][lrow] = posd;
      }
    }
  }
  __syncthreads();

  if (tid < BM) {                                     // combine + per-block loss
    const float d0 = rd_d[0][tid], d1 = rd_d[1][tid];
    const int   c0 = rd_c[0][tid], c1 = rd_c[1][tid];
    float bestd;
    if (d1 < d0 || (d1 == d0 && c1 < c0)) bestd = d1;
    else                                  bestd = d0;
    const float posd = fmaxf(rd_p[0][tid], rd_p[1][tid]);
    const float dap = posd, dan = bestd;
    const float dapn = dap / (dap + dan + 1e-8f);
    const float dann = dan / (dapn + dan + 1e-8f);    // sequential normalization
    float v = fmaxf(0.f, 1.5f * dapn - 0.8f * dann + 0.6f);
    #pragma unroll
    for (int sft = 1; sft < 64; sft <<= 1) v += __shfl_xor(v, sft);
    if (tid == 0) partials[blockIdx.x] = v;
  }

  // ---- finish tail: last ticket reduces all 512 partials ----
  __syncthreads();
  if (tid == 0) {
    __threadfence();
    tsh = atomicAdd(cnt2, 1u);
  }
  __syncthreads();
  if (tsh == (unsigned)(NB2 - 1)) {
    __threadfence();
    float* red = &f2s[0][0];                          // reuse 256-float LDS
    red[tid] = partials[tid] + partials[tid + 256];
    __syncthreads();
    for (int st = 128; st > 0; st >>= 1) {
      if (tid < st) red[tid] += red[tid + st];
      __syncthreads();
    }
    if (tid == 0) out[0] = fabsf(0.2f * (red[0] / (float)NSAMP));
  }
}

extern "C" void kernel_launch(void* const* d_in, const int* in_sizes, int n_in,
                              void* d_out, int out_size, void* d_ws, size_t ws_size,
                              hipStream_t stream) {
  const float* feat = (const float*)d_in[0];
  const int* labels = (const int*)d_in[1];
  float* out = (float*)d_out;

  char* ws = (char*)d_ws;
  unsigned short* protoI = (unsigned short*)ws;          // 16*8192*2 = 262144 B
  float* p2 = (float*)(ws + 262144);                     // 224 floats (pad 1K)
  float* partials = (float*)(ws + 263168);               // 512 floats = 2048 B
  unsigned int* cnt1 = (unsigned int*)(ws + 265216);     // tickets (256 B)
  unsigned int* cnt2 = (unsigned int*)(ws + 265216 + 128);
  float* psum = (float*)(ws + 266240);                   // 8*200*512*4 = 3276800 B
  int* pcnt = (int*)(ws + 266240 + 3276800);             // 1600 ints

  hipMemsetAsync(ws + 265216, 0, 256, stream);           // zero ticket counters
  k_proto<<<NB1, 512, 0, stream>>>(feat, labels, psum, pcnt, protoI, p2, cnt1);
  k_score<<<NB2, 256, 0, stream>>>(feat, labels, protoI, p2, partials, out, cnt2);
}

// Round 12
// 57.090 us; speedup vs baseline: 2.7850x; 2.7850x over previous
//
#include <hip/hip_runtime.h>
#include <hip/hip_bf16.h>

#define NCLS 200
#define NPADP 224       // logical proto rows = 14 x 16
#define NROWS 256       // padded rows in protoI image
#define NTW 7           // class tiles per wave (2 N-waves x 7 x 16 = 224)
#define DIM 512
#define NSAMP 32768
#define NSEG 8          // psum sample segments
#define CAP 32          // per-wave list capacity
#define BM 64           // sample rows per block
#define BK 32           // k per chunk
#define KIT 16          // DIM / BK
#define CHUS (NROWS*32) // ushorts per chunk image (8192)
#define NB2 512         // k_score grid

typedef __attribute__((ext_vector_type(4))) float f32x4;
typedef __attribute__((ext_vector_type(4))) int   i32x4;
typedef __attribute__((ext_vector_type(8))) short bf16x8;

__device__ inline short bf16s(float x) {
  __hip_bfloat16 h = __float2bfloat16(x);
  return *reinterpret_cast<short*>(&h);
}

__device__ inline bf16x8 pack8(f32x4 a, f32x4 b) {
  bf16x8 r;
  r[0] = bf16s(a[0]); r[1] = bf16s(a[1]); r[2] = bf16s(a[2]); r[3] = bf16s(a[3]);
  r[4] = bf16s(b[0]); r[5] = bf16s(b[1]); r[6] = bf16s(b[2]); r[7] = bf16s(b[3]);
  return r;
}

__device__ inline float sumsq(f32x4 a) {
  return a[0]*a[0] + a[1]*a[1] + a[2]*a[2] + a[3]*a[3];
}

// ---------------- Kernel 1a: per-(class, segment) partial sums -----------------
__global__ __launch_bounds__(512) void k_psum(
    const float* __restrict__ feat, const int* __restrict__ labels,
    float* __restrict__ psum, int* __restrict__ pcnt)
{
  const int bx = blockIdx.x;
  const int c = bx >> 3, s = bx & 7;
  const int tid = threadIdx.x;
  const int lane = tid & 63;
  const int w = tid >> 6;

  __shared__ int   lists[8][CAP];
  __shared__ int   cnts[8];
  __shared__ float partial[8][DIM];

  int cnt = 0;
  const int segbase = s * (NSAMP / NSEG) + w * (NSAMP / NSEG / 8);
  #pragma unroll
  for (int i = 0; i < 2; ++i) {
    const int base = segbase + i * 256 + lane * 4;
    const i32x4 lab4 = *(const i32x4*)(labels + base);
    #pragma unroll
    for (int u = 0; u < 4; ++u) {
      const bool m = (lab4[u] == c);
      const unsigned long long bal = __ballot(m);
      if (m) {
        const int pos = cnt + __popcll(bal & ((1ull << lane) - 1ull));
        if (pos < CAP) lists[w][pos] = base + u;
      }
      cnt += __popcll(bal);
    }
  }
  if (cnt > CAP) cnt = CAP;
  if (lane == 0) cnts[w] = cnt;

  float aE[8], aO[8];
  #pragma unroll
  for (int q = 0; q < 8; ++q) { aE[q] = 0.f; aO[q] = 0.f; }
  int j = 0;
  for (; j + 2 <= cnt; j += 2) {
    const int r0 = lists[w][j], r1 = lists[w][j + 1];
    const f32x4 a0 = *(const f32x4*)(feat + (size_t)r0 * DIM + lane * 8);
    const f32x4 b0 = *(const f32x4*)(feat + (size_t)r0 * DIM + lane * 8 + 4);
    const f32x4 a1 = *(const f32x4*)(feat + (size_t)r1 * DIM + lane * 8);
    const f32x4 b1 = *(const f32x4*)(feat + (size_t)r1 * DIM + lane * 8 + 4);
    aE[0] += a0[0]; aE[1] += a0[1]; aE[2] += a0[2]; aE[3] += a0[3];
    aE[4] += b0[0]; aE[5] += b0[1]; aE[6] += b0[2]; aE[7] += b0[3];
    aO[0] += a1[0]; aO[1] += a1[1]; aO[2] += a1[2]; aO[3] += a1[3];
    aO[4] += b1[0]; aO[5] += b1[1]; aO[6] += b1[2]; aO[7] += b1[3];
  }
  if (j < cnt) {
    const int r0 = lists[w][j];
    const f32x4 a0 = *(const f32x4*)(feat + (size_t)r0 * DIM + lane * 8);
    const f32x4 b0 = *(const f32x4*)(feat + (size_t)r0 * DIM + lane * 8 + 4);
    aE[0] += a0[0]; aE[1] += a0[1]; aE[2] += a0[2]; aE[3] += a0[3];
    aE[4] += b0[0]; aE[5] += b0[1]; aE[6] += b0[2]; aE[7] += b0[3];
  }
  #pragma unroll
  for (int q = 0; q < 8; ++q) partial[w][lane * 8 + q] = aE[q] + aO[q];
  __syncthreads();

  int total = 0;
  #pragma unroll
  for (int u = 0; u < 8; ++u) total += cnts[u];
  float sv = 0.f;
  #pragma unroll
  for (int u = 0; u < 8; ++u) sv += partial[u][tid];
  psum[(size_t)(s * NCLS + c) * DIM + tid] = sv;
  if (tid == 0) pcnt[s * NCLS + c] = total;
}

// ---------------- Kernel 1b: combine -> SWIZZLED chunk-major bf16 protos + p2 --
// protoI image: [chunk 0..15][row 0..255][4 units x 16B]; logical unit uL of
// row r stored at phys unit uL ^ ((r>>1)&3)  (conflict-free b128 reads after
// a LINEAR global_load_lds copy into LDS).
__global__ __launch_bounds__(256) void k_pcomb(
    const float* __restrict__ psum, const int* __restrict__ pcnt,
    unsigned short* __restrict__ protoI, float* __restrict__ p2out)
{
  const int c = blockIdx.x;
  const int tid = threadIdx.x;
  const int sw = (c >> 1) & 3;
  if (c >= NCLS) {     // zero classes 200..223 (rows 224..255 never read)
    #pragma unroll
    for (int h = 0; h < 2; ++h) {
      const int d = tid + h * 256;
      const int ck = d >> 5, uL = (d >> 3) & 3, e = d & 7;
      protoI[(size_t)ck * CHUS + c * 32 + (uL ^ sw) * 8 + e] = 0;
    }
    if (tid == 0) p2out[c] = 1e30f;
    return;
  }
  __shared__ float red[256];
  float a0 = 0.f, a1 = 0.f;
  int total = 0;
  #pragma unroll
  for (int s = 0; s < NSEG; ++s) {     // fixed combine order: deterministic
    a0 += psum[(size_t)(s * NCLS + c) * DIM + tid];
    a1 += psum[(size_t)(s * NCLS + c) * DIM + 256 + tid];
    total += pcnt[s * NCLS + c];
  }
  const float inv = 1.0f / ((float)total + 1e-8f);   // counts + EPS
  const float p0 = a0 * inv, p1 = a1 * inv;
  {
    const int d = tid;
    const int ck = d >> 5, uL = (d >> 3) & 3, e = d & 7;
    protoI[(size_t)ck * CHUS + c * 32 + (uL ^ sw) * 8 + e] = (unsigned short)bf16s(p0);
  }
  {
    const int d = tid + 256;
    const int ck = d >> 5, uL = (d >> 3) & 3, e = d & 7;
    protoI[(size_t)ck * CHUS + c * 32 + (uL ^ sw) * 8 + e] = (unsigned short)bf16s(p1);
  }

  red[tid] = p0 * p0 + p1 * p1;
  __syncthreads();
  for (int st = 128; st > 0; st >>= 1) {
    if (tid < st) red[tid] += red[tid + st];
    __syncthreads();
  }
  if (tid == 0) p2out[c] = red[0];
}

// ---------------- Kernel 2: gload_lds-B MFMA GEMM + argmin + loss + finish -----
// R10's proven k_score, verbatim, plus the R11-proven last-ticket finish tail
// (no polling: 511 blocks ticket+exit; the single last block reduces partials).
__global__ __launch_bounds__(256) void k_score(
    const float* __restrict__ feat, const int* __restrict__ labels,
    const unsigned short* __restrict__ protoI, const float* __restrict__ p2,
    float* __restrict__ partials, float* __restrict__ out,
    unsigned int* __restrict__ cnt2)
{
  __shared__ __align__(16) unsigned short As[2][BM * BK];    // 8 KiB
  __shared__ __align__(1024) unsigned short Bs[2][CHUS];     // 32 KiB
  __shared__ float f2s[BM][4];
  __shared__ float rd_d[2][BM];
  __shared__ int   rd_c[2][BM];
  __shared__ float rd_p[2][BM];
  __shared__ unsigned int tsh;

  const int tid = threadIdx.x;
  const int lane = tid & 63;
  const int w = tid >> 6;
  const int wm = w >> 1, wn = w & 1;
  const int lr = lane & 15;
  const int kg = lane >> 4;
  const int blockRow = blockIdx.x * BM;

  // A staging: 4 threads/row, 8 floats each; XOR-swizzled 16B units
  const int arow = tid >> 2, apart = tid & 3;
  const float* agp = feat + (size_t)(blockRow + arow) * DIM + apart * 8;
  const int aoff = arow * BK + ((apart ^ (arow & 3)) * 8);

  float f2part = 0.f;

  f32x4 acc0[NTW], acc1[NTW];
  #pragma unroll
  for (int n = 0; n < NTW; ++n) {
    acc0[n] = f32x4{0.f, 0.f, 0.f, 0.f};
    acc1[n] = f32x4{0.f, 0.f, 0.f, 0.f};
  }

  const int r0v = wm * 32 + lr;
  const int r1v = r0v + 16;
  const int ar0 = r0v * BK + ((kg ^ (r0v & 3)) * 8);
  const int ar1 = r1v * BK + ((kg ^ (r1v & 3)) * 8);

#define ISSUE_A(T, S) do {                                                      \
    const float* ag_ = agp + (T) * BK;                                          \
    S##0 = *(const f32x4*)(ag_);                                                \
    S##1 = *(const f32x4*)(ag_ + 4);                                            \
  } while (0)

#define STOREA(NB, S) do {                                                      \
    f2part += sumsq(S##0) + sumsq(S##1);                                        \
    *(bf16x8*)&As[NB][aoff] = pack8(S##0, S##1);                                \
  } while (0)

#define BGLD(T, NB) do {                                                        \
    _Pragma("unroll")                                                           \
    for (int i_ = 0; i_ < 4; ++i_) {                                            \
      const int j_ = w * 4 + i_;                                                \
      const unsigned short* g_ = protoI + (size_t)(T) * CHUS + j_ * 512 + lane * 8; \
      unsigned short* l_ = &Bs[NB][j_ * 512];                                   \
      __builtin_amdgcn_global_load_lds(                                         \
          (const __attribute__((address_space(1))) void*)g_,                    \
          (__attribute__((address_space(3))) void*)l_, 16, 0, 0);               \
    }                                                                           \
  } while (0)

#define COMPUTE(CUR) do {                                                       \
    const bf16x8 Af0 = *(const bf16x8*)&As[CUR][ar0];                           \
    const bf16x8 Af1 = *(const bf16x8*)&As[CUR][ar1];                           \
    _Pragma("unroll")                                                           \
    for (int n = 0; n < NTW; ++n) {                                             \
      const int row_ = wn * 112 + n * 16 + lr;                                  \
      const bf16x8 Bf = *(const bf16x8*)&Bs[CUR][row_ * 32 + ((kg ^ ((row_ >> 1) & 3)) * 8)]; \
      acc0[n] = __builtin_amdgcn_mfma_f32_16x16x32_bf16(Af0, Bf, acc0[n], 0, 0, 0); \
      acc1[n] = __builtin_amdgcn_mfma_f32_16x16x32_bf16(Af1, Bf, acc1[n], 0, 0, 0); \
    }                                                                           \
  } while (0)

#define BAR_VM2() do {                                                          \
    asm volatile("s_waitcnt vmcnt(2)" ::: "memory");                            \
    asm volatile("s_waitcnt lgkmcnt(0)" ::: "memory");                          \
    __builtin_amdgcn_s_barrier();                                               \
  } while (0)

#define BAR_VM0() do {                                                          \
    asm volatile("s_waitcnt vmcnt(0)" ::: "memory");                            \
    asm volatile("s_waitcnt lgkmcnt(0)" ::: "memory");                          \
    __builtin_amdgcn_s_barrier();                                               \
  } while (0)

  f32x4 AE_0, AE_1;   // even-chunk A regs
  f32x4 AO_0, AO_1;   // odd-chunk A regs

  // ---- prologue ----
  ISSUE_A(0, AE_);
  BGLD(0, 0);
  __builtin_amdgcn_sched_barrier(0);
  ISSUE_A(1, AO_);
  STOREA(0, AE_);                 // auto-waits AE loads (drains BGLD0 too: ok)
  BAR_VM2();                      // keep AO in flight

  // ---- 16 chunk phases ----
  #pragma unroll
  for (int t = 0; t < KIT; ++t) {
    const int cur = t & 1;
    const int nxt = cur ^ 1;
    if (t + 1 < KIT) {
      if ((t & 1) == 0) STOREA(nxt, AO_); else STOREA(nxt, AE_);
      BGLD(t + 1, nxt);
      __builtin_amdgcn_sched_barrier(0);
    }
    if (t + 2 < KIT) {
      if ((t & 1) == 0) ISSUE_A(t + 2, AE_); else ISSUE_A(t + 2, AO_);
    }
    COMPUTE(cur);
    if (t + 1 < KIT) {
      if (t + 2 < KIT) BAR_VM2(); else BAR_VM0();
    }
  }
#undef ISSUE_A
#undef STOREA
#undef BGLD
#undef COMPUTE
#undef BAR_VM2
#undef BAR_VM0

  // exact per-row-part f2 (fixed combine order)
  f2s[arow][apart] = f2part;
  __syncthreads();

  float p2v[NTW];
  #pragma unroll
  for (int n = 0; n < NTW; ++n) p2v[n] = p2[wn * 112 + n * 16 + lr];

  #pragma unroll
  for (int m = 0; m < 2; ++m) {
    #pragma unroll
    for (int r = 0; r < 4; ++r) {
      const int srow = kg * 4 + r;                    // C/D row within 16-tile
      const int lrow = wm * 32 + m * 16 + srow;       // block-local sample row
      const float f2v = (f2s[lrow][0] + f2s[lrow][1]) + (f2s[lrow][2] + f2s[lrow][3]);
      const int lab = labels[blockRow + lrow];
      float bestd = 1e38f; int bestc = 1 << 30;
      float posd = -1.f;
      #pragma unroll
      for (int n = 0; n < NTW; ++n) {
        const int cidx = wn * 112 + n * 16 + lr;      // C/D col = class
        const float sc = (m == 0) ? acc0[n][r] : acc1[n][r];
        const float d2 = fmaxf(f2v + p2v[n] - 2.0f * sc, 0.0f);
        if (cidx == lab) posd = d2;
        else if (cidx < NCLS &&
                 (d2 < bestd || (d2 == bestd && cidx < bestc))) { bestd = d2; bestc = cidx; }
      }
      #pragma unroll
      for (int sft = 1; sft < 16; sft <<= 1) {        // 16-lane group reduce
        const float od = __shfl_xor(bestd, sft);
        const int   oc = __shfl_xor(bestc, sft);
        const float op = __shfl_xor(posd, sft);
        if (od < bestd || (od == bestd && oc < bestc)) { bestd = od; bestc = oc; }
        posd = fmaxf(posd, op);
      }
      if (lr == 0) {
        rd_d[wn][lrow] = bestd; rd_c[wn][lrow] = bestc; rd_p[wn][lrow] = posd;
      }
    }
  }
  __syncthreads();

  if (tid < BM) {                                     // combine + per-block loss
    const float d0 = rd_d[0][tid], d1 = rd_d[1][tid];
    const int   c0 = rd_c[0][tid], c1 = rd_c[1][tid];
    float bestd;
    if (d1 < d0 || (d1 == d0 && c1 < c0)) bestd = d1;
    else                                  bestd = d0;
    const float posd = fmaxf(rd_p[0][tid], rd_p[1][tid]);
    const float dap = posd, dan = bestd;
    const float dapn = dap / (dap + dan + 1e-8f);
    const float dann = dan / (dapn + dan + 1e-8f);    // sequential normalization
    float v = fmaxf(0.f, 1.5f * dapn - 0.8f * dann + 0.6f);
    #pragma unroll
    for (int sft = 1; sft < 64; sft <<= 1) v += __shfl_xor(v, sft);
    if (tid == 0) partials[blockIdx.x] = v;
  }

  // ---- finish tail: last ticket (no polling) reduces all 512 partials ----
  __syncthreads();
  if (tid == 0) {
    __threadfence();
    tsh = atomicAdd(cnt2, 1u);
  }
  __syncthreads();
  if (tsh == (unsigned)(NB2 - 1)) {
    __threadfence();
    float* red = &f2s[0][0];                          // reuse 256-float LDS
    red[tid] = partials[tid] + partials[tid + 256];
    __syncthreads();
    for (int st = 128; st > 0; st >>= 1) {
      if (tid < st) red[tid] += red[tid + st];
      __syncthreads();
    }
    if (tid == 0) out[0] = fabsf(0.2f * (red[0] / (float)NSAMP));
  }
}

extern "C" void kernel_launch(void* const* d_in, const int* in_sizes, int n_in,
                              void* d_out, int out_size, void* d_ws, size_t ws_size,
                              hipStream_t stream) {
  const float* feat = (const float*)d_in[0];
  const int* labels = (const int*)d_in[1];
  float* out = (float*)d_out;

  char* ws = (char*)d_ws;
  unsigned short* protoI = (unsigned short*)ws;          // 16*8192*2 = 262144 B
  float* p2 = (float*)(ws + 262144);                     // 224 floats (pad 1K)
  float* partials = (float*)(ws + 263168);               // 512 floats = 2048 B
  unsigned int* cnt2 = (unsigned int*)(ws + 265216);     // ticket counter
  float* psum = (float*)(ws + 266240);                   // 8*200*512*4 = 3276800 B
  int* pcnt = (int*)(ws + 266240 + 3276800);             // 1600 ints

  hipMemsetAsync(ws + 265216, 0, 128, stream);           // zero ticket counter
  k_psum<<<NSEG * NCLS, 512, 0, stream>>>(feat, labels, psum, pcnt);
  k_pcomb<<<NPADP, 256, 0, stream>>>(psum, pcnt, protoI, p2);
  k_score<<<NB2, 256, 0, stream>>>(feat, labels, protoI, p2, partials, out, cnt2);
}

// Round 13
// 52.333 us; speedup vs baseline: 3.0382x; 1.0909x over previous
//
#include <hip/hip_runtime.h>
#include <hip/hip_bf16.h>

#define NCLS 200
#define NPADP 224       // logical proto rows = 14 x 16
#define NROWS 256       // padded rows in protoI image
#define NTW 7           // class tiles per wave (2 N-waves x 7 x 16 = 224)
#define DIM 512
#define NSAMP 32768
#define NSEG 8          // psum sample segments
#define CAP 32          // per-wave list capacity
#define BM 64           // sample rows per block
#define BK 32           // k per chunk
#define KIT 16          // DIM / BK
#define CHUS (NROWS*32) // ushorts per chunk image (8192)
#define NB2 512         // k_score grid

typedef __attribute__((ext_vector_type(4))) float f32x4;
typedef __attribute__((ext_vector_type(4))) int   i32x4;
typedef __attribute__((ext_vector_type(8))) short bf16x8;

__device__ inline short bf16s(float x) {
  __hip_bfloat16 h = __float2bfloat16(x);
  return *reinterpret_cast<short*>(&h);
}

__device__ inline bf16x8 pack8(f32x4 a, f32x4 b) {
  bf16x8 r;
  r[0] = bf16s(a[0]); r[1] = bf16s(a[1]); r[2] = bf16s(a[2]); r[3] = bf16s(a[3]);
  r[4] = bf16s(b[0]); r[5] = bf16s(b[1]); r[6] = bf16s(b[2]); r[7] = bf16s(b[3]);
  return r;
}

__device__ inline float sumsq(f32x4 a) {
  return a[0]*a[0] + a[1]*a[1] + a[2]*a[2] + a[3]*a[3];
}

// ---------------- Kernel 1a: per-(class, segment) partial sums -----------------
__global__ __launch_bounds__(512) void k_psum(
    const float* __restrict__ feat, const int* __restrict__ labels,
    float* __restrict__ psum, int* __restrict__ pcnt)
{
  const int bx = blockIdx.x;
  const int c = bx >> 3, s = bx & 7;
  const int tid = threadIdx.x;
  const int lane = tid & 63;
  const int w = tid >> 6;

  __shared__ int   lists[8][CAP];
  __shared__ int   cnts[8];
  __shared__ float partial[8][DIM];

  int cnt = 0;
  const int segbase = s * (NSAMP / NSEG) + w * (NSAMP / NSEG / 8);
  #pragma unroll
  for (int i = 0; i < 2; ++i) {
    const int base = segbase + i * 256 + lane * 4;
    const i32x4 lab4 = *(const i32x4*)(labels + base);
    #pragma unroll
    for (int u = 0; u < 4; ++u) {
      const bool m = (lab4[u] == c);
      const unsigned long long bal = __ballot(m);
      if (m) {
        const int pos = cnt + __popcll(bal & ((1ull << lane) - 1ull));
        if (pos < CAP) lists[w][pos] = base + u;
      }
      cnt += __popcll(bal);
    }
  }
  if (cnt > CAP) cnt = CAP;
  if (lane == 0) cnts[w] = cnt;

  float aE[8], aO[8];
  #pragma unroll
  for (int q = 0; q < 8; ++q) { aE[q] = 0.f; aO[q] = 0.f; }
  int j = 0;
  for (; j + 2 <= cnt; j += 2) {
    const int r0 = lists[w][j], r1 = lists[w][j + 1];
    const f32x4 a0 = *(const f32x4*)(feat + (size_t)r0 * DIM + lane * 8);
    const f32x4 b0 = *(const f32x4*)(feat + (size_t)r0 * DIM + lane * 8 + 4);
    const f32x4 a1 = *(const f32x4*)(feat + (size_t)r1 * DIM + lane * 8);
    const f32x4 b1 = *(const f32x4*)(feat + (size_t)r1 * DIM + lane * 8 + 4);
    aE[0] += a0[0]; aE[1] += a0[1]; aE[2] += a0[2]; aE[3] += a0[3];
    aE[4] += b0[0]; aE[5] += b0[1]; aE[6] += b0[2]; aE[7] += b0[3];
    aO[0] += a1[0]; aO[1] += a1[1]; aO[2] += a1[2]; aO[3] += a1[3];
    aO[4] += b1[0]; aO[5] += b1[1]; aO[6] += b1[2]; aO[7] += b1[3];
  }
  if (j < cnt) {
    const int r0 = lists[w][j];
    const f32x4 a0 = *(const f32x4*)(feat + (size_t)r0 * DIM + lane * 8);
    const f32x4 b0 = *(const f32x4*)(feat + (size_t)r0 * DIM + lane * 8 + 4);
    aE[0] += a0[0]; aE[1] += a0[1]; aE[2] += a0[2]; aE[3] += a0[3];
    aE[4] += b0[0]; aE[5] += b0[1]; aE[6] += b0[2]; aE[7] += b0[3];
  }
  #pragma unroll
  for (int q = 0; q < 8; ++q) partial[w][lane * 8 + q] = aE[q] + aO[q];
  __syncthreads();

  int total = 0;
  #pragma unroll
  for (int u = 0; u < 8; ++u) total += cnts[u];
  float sv = 0.f;
  #pragma unroll
  for (int u = 0; u < 8; ++u) sv += partial[u][tid];
  psum[(size_t)(s * NCLS + c) * DIM + tid] = sv;
  if (tid == 0) pcnt[s * NCLS + c] = total;
}

// ---------------- Kernel 1b: combine -> SWIZZLED chunk-major bf16 protos + p2 --
// Also zeroes the k_score ticket counter (block 0) — replaces the costly
// hipMemsetAsync dispatch (R12 evidence: 128-B fill cost ~40 us/replay).
__global__ __launch_bounds__(256) void k_pcomb(
    const float* __restrict__ psum, const int* __restrict__ pcnt,
    unsigned short* __restrict__ protoI, float* __restrict__ p2out,
    unsigned int* __restrict__ cnt2)
{
  const int c = blockIdx.x;
  const int tid = threadIdx.x;
  if (c == 0 && tid == 0) *cnt2 = 0;   // visible to k_score via stream order
  const int sw = (c >> 1) & 3;
  if (c >= NCLS) {     // zero classes 200..223 (rows 224..255 never read)
    #pragma unroll
    for (int h = 0; h < 2; ++h) {
      const int d = tid + h * 256;
      const int ck = d >> 5, uL = (d >> 3) & 3, e = d & 7;
      protoI[(size_t)ck * CHUS + c * 32 + (uL ^ sw) * 8 + e] = 0;
    }
    if (tid == 0) p2out[c] = 1e30f;
    return;
  }
  __shared__ float red[256];
  float a0 = 0.f, a1 = 0.f;
  int total = 0;
  #pragma unroll
  for (int s = 0; s < NSEG; ++s) {     // fixed combine order: deterministic
    a0 += psum[(size_t)(s * NCLS + c) * DIM + tid];
    a1 += psum[(size_t)(s * NCLS + c) * DIM + 256 + tid];
    total += pcnt[s * NCLS + c];
  }
  const float inv = 1.0f / ((float)total + 1e-8f);   // counts + EPS
  const float p0 = a0 * inv, p1 = a1 * inv;
  {
    const int d = tid;
    const int ck = d >> 5, uL = (d >> 3) & 3, e = d & 7;
    protoI[(size_t)ck * CHUS + c * 32 + (uL ^ sw) * 8 + e] = (unsigned short)bf16s(p0);
  }
  {
    const int d = tid + 256;
    const int ck = d >> 5, uL = (d >> 3) & 3, e = d & 7;
    protoI[(size_t)ck * CHUS + c * 32 + (uL ^ sw) * 8 + e] = (unsigned short)bf16s(p1);
  }

  red[tid] = p0 * p0 + p1 * p1;
  __syncthreads();
  for (int st = 128; st > 0; st >>= 1) {
    if (tid < st) red[tid] += red[tid + st];
    __syncthreads();
  }
  if (tid == 0) p2out[c] = red[0];
}

// ---------------- Kernel 2: gload_lds-B MFMA GEMM + argmin + loss + finish -----
// R10's proven k_score, verbatim, plus the proven last-ticket finish tail
// (no polling: 511 blocks ticket+exit; the single last block reduces partials).
__global__ __launch_bounds__(256) void k_score(
    const float* __restrict__ feat, const int* __restrict__ labels,
    const unsigned short* __restrict__ protoI, const float* __restrict__ p2,
    float* __restrict__ partials, float* __restrict__ out,
    unsigned int* __restrict__ cnt2)
{
  __shared__ __align__(16) unsigned short As[2][BM * BK];    // 8 KiB
  __shared__ __align__(1024) unsigned short Bs[2][CHUS];     // 32 KiB
  __shared__ float f2s[BM][4];
  __shared__ float rd_d[2][BM];
  __shared__ int   rd_c[2][BM];
  __shared__ float rd_p[2][BM];
  __shared__ unsigned int tsh;

  const int tid = threadIdx.x;
  const int lane = tid & 63;
  const int w = tid >> 6;
  const int wm = w >> 1, wn = w & 1;
  const int lr = lane & 15;
  const int kg = lane >> 4;
  const int blockRow = blockIdx.x * BM;

  // A staging: 4 threads/row, 8 floats each; XOR-swizzled 16B units
  const int arow = tid >> 2, apart = tid & 3;
  const float* agp = feat + (size_t)(blockRow + arow) * DIM + apart * 8;
  const int aoff = arow * BK + ((apart ^ (arow & 3)) * 8);

  float f2part = 0.f;

  f32x4 acc0[NTW], acc1[NTW];
  #pragma unroll
  for (int n = 0; n < NTW; ++n) {
    acc0[n] = f32x4{0.f, 0.f, 0.f, 0.f};
    acc1[n] = f32x4{0.f, 0.f, 0.f, 0.f};
  }

  const int r0v = wm * 32 + lr;
  const int r1v = r0v + 16;
  const int ar0 = r0v * BK + ((kg ^ (r0v & 3)) * 8);
  const int ar1 = r1v * BK + ((kg ^ (r1v & 3)) * 8);

#define ISSUE_A(T, S) do {                                                      \
    const float* ag_ = agp + (T) * BK;                                          \
    S##0 = *(const f32x4*)(ag_);                                                \
    S##1 = *(const f32x4*)(ag_ + 4);                                            \
  } while (0)

#define STOREA(NB, S) do {                                                      \
    f2part += sumsq(S##0) + sumsq(S##1);                                        \
    *(bf16x8*)&As[NB][aoff] = pack8(S##0, S##1);                                \
  } while (0)

#define BGLD(T, NB) do {                                                        \
    _Pragma("unroll")                                                           \
    for (int i_ = 0; i_ < 4; ++i_) {                                            \
      const int j_ = w * 4 + i_;                                                \
      const unsigned short* g_ = protoI + (size_t)(T) * CHUS + j_ * 512 + lane * 8; \
      unsigned short* l_ = &Bs[NB][j_ * 512];                                   \
      __builtin_amdgcn_global_load_lds(                                         \
          (const __attribute__((address_space(1))) void*)g_,                    \
          (__attribute__((address_space(3))) void*)l_, 16, 0, 0);               \
    }                                                                           \
  } while (0)

#define COMPUTE(CUR) do {                                                       \
    const bf16x8 Af0 = *(const bf16x8*)&As[CUR][ar0];                           \
    const bf16x8 Af1 = *(const bf16x8*)&As[CUR][ar1];                           \
    _Pragma("unroll")                                                           \
    for (int n = 0; n < NTW; ++n) {                                             \
      const int row_ = wn * 112 + n * 16 + lr;                                  \
      const bf16x8 Bf = *(const bf16x8*)&Bs[CUR][row_ * 32 + ((kg ^ ((row_ >> 1) & 3)) * 8)]; \
      acc0[n] = __builtin_amdgcn_mfma_f32_16x16x32_bf16(Af0, Bf, acc0[n], 0, 0, 0); \
      acc1[n] = __builtin_amdgcn_mfma_f32_16x16x32_bf16(Af1, Bf, acc1[n], 0, 0, 0); \
    }                                                                           \
  } while (0)

#define BAR_VM2() do {                                                          \
    asm volatile("s_waitcnt vmcnt(2)" ::: "memory");                            \
    asm volatile("s_waitcnt lgkmcnt(0)" ::: "memory");                          \
    __builtin_amdgcn_s_barrier();                                               \
  } while (0)

#define BAR_VM0() do {                                                          \
    asm volatile("s_waitcnt vmcnt(0)" ::: "memory");                            \
    asm volatile("s_waitcnt lgkmcnt(0)" ::: "memory");                          \
    __builtin_amdgcn_s_barrier();                                               \
  } while (0)

  f32x4 AE_0, AE_1;   // even-chunk A regs
  f32x4 AO_0, AO_1;   // odd-chunk A regs

  // ---- prologue ----
  ISSUE_A(0, AE_);
  BGLD(0, 0);
  __builtin_amdgcn_sched_barrier(0);
  ISSUE_A(1, AO_);
  STOREA(0, AE_);                 // auto-waits AE loads (drains BGLD0 too: ok)
  BAR_VM2();                      // keep AO in flight

  // ---- 16 chunk phases ----
  #pragma unroll
  for (int t = 0; t < KIT; ++t) {
    const int cur = t & 1;
    const int nxt = cur ^ 1;
    if (t + 1 < KIT) {
      if ((t & 1) == 0) STOREA(nxt, AO_); else STOREA(nxt, AE_);
      BGLD(t + 1, nxt);
      __builtin_amdgcn_sched_barrier(0);
    }
    if (t + 2 < KIT) {
      if ((t & 1) == 0) ISSUE_A(t + 2, AE_); else ISSUE_A(t + 2, AO_);
    }
    COMPUTE(cur);
    if (t + 1 < KIT) {
      if (t + 2 < KIT) BAR_VM2(); else BAR_VM0();
    }
  }
#undef ISSUE_A
#undef STOREA
#undef BGLD
#undef COMPUTE
#undef BAR_VM2
#undef BAR_VM0

  // exact per-row-part f2 (fixed combine order)
  f2s[arow][apart] = f2part;
  __syncthreads();

  float p2v[NTW];
  #pragma unroll
  for (int n = 0; n < NTW; ++n) p2v[n] = p2[wn * 112 + n * 16 + lr];

  #pragma unroll
  for (int m = 0; m < 2; ++m) {
    #pragma unroll
    for (int r = 0; r < 4; ++r) {
      const int srow = kg * 4 + r;                    // C/D row within 16-tile
      const int lrow = wm * 32 + m * 16 + srow;       // block-local sample row
      const float f2v = (f2s[lrow][0] + f2s[lrow][1]) + (f2s[lrow][2] + f2s[lrow][3]);
      const int lab = labels[blockRow + lrow];
      float bestd = 1e38f; int bestc = 1 << 30;
      float posd = -1.f;
      #pragma unroll
      for (int n = 0; n < NTW; ++n) {
        const int cidx = wn * 112 + n * 16 + lr;      // C/D col = class
        const float sc = (m == 0) ? acc0[n][r] : acc1[n][r];
        const float d2 = fmaxf(f2v + p2v[n] - 2.0f * sc, 0.0f);
        if (cidx == lab) posd = d2;
        else if (cidx < NCLS &&
                 (d2 < bestd || (d2 == bestd && cidx < bestc))) { bestd = d2; bestc = cidx; }
      }
      #pragma unroll
      for (int sft = 1; sft < 16; sft <<= 1) {        // 16-lane group reduce
        const float od = __shfl_xor(bestd, sft);
        const int   oc = __shfl_xor(bestc, sft);
        const float op = __shfl_xor(posd, sft);
        if (od < bestd || (od == bestd && oc < bestc)) { bestd = od; bestc = oc; }
        posd = fmaxf(posd, op);
      }
      if (lr == 0) {
        rd_d[wn][lrow] = bestd; rd_c[wn][lrow] = bestc; rd_p[wn][lrow] = posd;
      }
    }
  }
  __syncthreads();

  if (tid < BM) {                                     // combine + per-block loss
    const float d0 = rd_d[0][tid], d1 = rd_d[1][tid];
    const int   c0 = rd_c[0][tid], c1 = rd_c[1][tid];
    float bestd;
    if (d1 < d0 || (d1 == d0 && c1 < c0)) bestd = d1;
    else                                  bestd = d0;
    const float posd = fmaxf(rd_p[0][tid], rd_p[1][tid]);
    const float dap = posd, dan = bestd;
    const float dapn = dap / (dap + dan + 1e-8f);
    const float dann = dan / (dapn + dan + 1e-8f);    // sequential normalization
    float v = fmaxf(0.f, 1.5f * dapn - 0.8f * dann + 0.6f);
    #pragma unroll
    for (int sft = 1; sft < 64; sft <<= 1) v += __shfl_xor(v, sft);
    if (tid == 0) partials[blockIdx.x] = v;
  }

  // ---- finish tail: last ticket (no polling) reduces all 512 partials ----
  __syncthreads();
  if (tid == 0) {
    __threadfence();
    tsh = atomicAdd(cnt2, 1u);
  }
  __syncthreads();
  if (tsh == (unsigned)(NB2 - 1)) {
    __threadfence();
    float* red = &f2s[0][0];                          // reuse 256-float LDS
    red[tid] = partials[tid] + partials[tid + 256];
    __syncthreads();
    for (int st = 128; st > 0; st >>= 1) {
      if (tid < st) red[tid] += red[tid + st];
      __syncthreads();
    }
    if (tid == 0) out[0] = fabsf(0.2f * (red[0] / (float)NSAMP));
  }
}

extern "C" void kernel_launch(void* const* d_in, const int* in_sizes, int n_in,
                              void* d_out, int out_size, void* d_ws, size_t ws_size,
                              hipStream_t stream) {
  const float* feat = (const float*)d_in[0];
  const int* labels = (const int*)d_in[1];
  float* out = (float*)d_out;

  char* ws = (char*)d_ws;
  unsigned short* protoI = (unsigned short*)ws;          // 16*8192*2 = 262144 B
  float* p2 = (float*)(ws + 262144);                     // 224 floats (pad 1K)
  float* partials = (float*)(ws + 263168);               // 512 floats = 2048 B
  unsigned int* cnt2 = (unsigned int*)(ws + 265216);     // ticket counter
  float* psum = (float*)(ws + 266240);                   // 8*200*512*4 = 3276800 B
  int* pcnt = (int*)(ws + 266240 + 3276800);             // 1600 ints

  k_psum<<<NSEG * NCLS, 512, 0, stream>>>(feat, labels, psum, pcnt);
  k_pcomb<<<NPADP, 256, 0, stream>>>(psum, pcnt, protoI, p2, cnt2);
  k_score<<<NB2, 256, 0, stream>>>(feat, labels, protoI, p2, partials, out, cnt2);
}

// Round 14
// 43.729 us; speedup vs baseline: 3.6360x; 1.1968x over previous
//
#include <hip/hip_runtime.h>
#include <hip/hip_bf16.h>

#define NCLS 200
#define NPADP 224       // logical proto rows = 14 x 16
#define NROWS 256       // padded rows in protoI image
#define NTW 7           // class tiles per wave (2 N-waves x 7 x 16 = 224)
#define DIM 512
#define NSAMP 32768
#define NSEG 8          // psum sample segments
#define CAP 32          // per-wave list capacity
#define BM 64           // sample rows per block
#define BK 32           // k per chunk
#define KIT 16          // DIM / BK
#define CHUS (NROWS*32) // ushorts per chunk image (8192)

typedef __attribute__((ext_vector_type(4))) float f32x4;
typedef __attribute__((ext_vector_type(4))) int   i32x4;
typedef __attribute__((ext_vector_type(8))) short bf16x8;

__device__ inline short bf16s(float x) {
  __hip_bfloat16 h = __float2bfloat16(x);
  return *reinterpret_cast<short*>(&h);
}

__device__ inline bf16x8 pack8(f32x4 a, f32x4 b) {
  bf16x8 r;
  r[0] = bf16s(a[0]); r[1] = bf16s(a[1]); r[2] = bf16s(a[2]); r[3] = bf16s(a[3]);
  r[4] = bf16s(b[0]); r[5] = bf16s(b[1]); r[6] = bf16s(b[2]); r[7] = bf16s(b[3]);
  return r;
}

__device__ inline float sumsq(f32x4 a) {
  return a[0]*a[0] + a[1]*a[1] + a[2]*a[2] + a[3]*a[3];
}

// ---------------- Kernel 1a: per-(class, segment) partial sums -----------------
__global__ __launch_bounds__(512) void k_psum(
    const float* __restrict__ feat, const int* __restrict__ labels,
    float* __restrict__ psum, int* __restrict__ pcnt)
{
  const int bx = blockIdx.x;
  const int c = bx >> 3, s = bx & 7;
  const int tid = threadIdx.x;
  const int lane = tid & 63;
  const int w = tid >> 6;

  __shared__ int   lists[8][CAP];
  __shared__ int   cnts[8];
  __shared__ float partial[8][DIM];

  int cnt = 0;
  const int segbase = s * (NSAMP / NSEG) + w * (NSAMP / NSEG / 8);
  #pragma unroll
  for (int i = 0; i < 2; ++i) {
    const int base = segbase + i * 256 + lane * 4;
    const i32x4 lab4 = *(const i32x4*)(labels + base);
    #pragma unroll
    for (int u = 0; u < 4; ++u) {
      const bool m = (lab4[u] == c);
      const unsigned long long bal = __ballot(m);
      if (m) {
        const int pos = cnt + __popcll(bal & ((1ull << lane) - 1ull));
        if (pos < CAP) lists[w][pos] = base + u;
      }
      cnt += __popcll(bal);
    }
  }
  if (cnt > CAP) cnt = CAP;
  if (lane == 0) cnts[w] = cnt;

  float aE[8], aO[8];
  #pragma unroll
  for (int q = 0; q < 8; ++q) { aE[q] = 0.f; aO[q] = 0.f; }
  int j = 0;
  for (; j + 2 <= cnt; j += 2) {
    const int r0 = lists[w][j], r1 = lists[w][j + 1];
    const f32x4 a0 = *(const f32x4*)(feat + (size_t)r0 * DIM + lane * 8);
    const f32x4 b0 = *(const f32x4*)(feat + (size_t)r0 * DIM + lane * 8 + 4);
    const f32x4 a1 = *(const f32x4*)(feat + (size_t)r1 * DIM + lane * 8);
    const f32x4 b1 = *(const f32x4*)(feat + (size_t)r1 * DIM + lane * 8 + 4);
    aE[0] += a0[0]; aE[1] += a0[1]; aE[2] += a0[2]; aE[3] += a0[3];
    aE[4] += b0[0]; aE[5] += b0[1]; aE[6] += b0[2]; aE[7] += b0[3];
    aO[0] += a1[0]; aO[1] += a1[1]; aO[2] += a1[2]; aO[3] += a1[3];
    aO[4] += b1[0]; aO[5] += b1[1]; aO[6] += b1[2]; aO[7] += b1[3];
  }
  if (j < cnt) {
    const int r0 = lists[w][j];
    const f32x4 a0 = *(const f32x4*)(feat + (size_t)r0 * DIM + lane * 8);
    const f32x4 b0 = *(const f32x4*)(feat + (size_t)r0 * DIM + lane * 8 + 4);
    aE[0] += a0[0]; aE[1] += a0[1]; aE[2] += a0[2]; aE[3] += a0[3];
    aE[4] += b0[0]; aE[5] += b0[1]; aE[6] += b0[2]; aE[7] += b0[3];
  }
  #pragma unroll
  for (int q = 0; q < 8; ++q) partial[w][lane * 8 + q] = aE[q] + aO[q];
  __syncthreads();

  int total = 0;
  #pragma unroll
  for (int u = 0; u < 8; ++u) total += cnts[u];
  float sv = 0.f;
  #pragma unroll
  for (int u = 0; u < 8; ++u) sv += partial[u][tid];
  psum[(size_t)(s * NCLS + c) * DIM + tid] = sv;
  if (tid == 0) pcnt[s * NCLS + c] = total;
}

// ---------------- Kernel 1b: combine -> SWIZZLED chunk-major bf16 protos + p2 --
__global__ __launch_bounds__(256) void k_pcomb(
    const float* __restrict__ psum, const int* __restrict__ pcnt,
    unsigned short* __restrict__ protoI, float* __restrict__ p2out)
{
  const int c = blockIdx.x;
  const int tid = threadIdx.x;
  const int sw = (c >> 1) & 3;
  if (c >= NCLS) {     // zero classes 200..223 (rows 224..255 never read)
    #pragma unroll
    for (int h = 0; h < 2; ++h) {
      const int d = tid + h * 256;
      const int ck = d >> 5, uL = (d >> 3) & 3, e = d & 7;
      protoI[(size_t)ck * CHUS + c * 32 + (uL ^ sw) * 8 + e] = 0;
    }
    if (tid == 0) p2out[c] = 1e30f;
    return;
  }
  __shared__ float red[256];
  float a0 = 0.f, a1 = 0.f;
  int total = 0;
  #pragma unroll
  for (int s = 0; s < NSEG; ++s) {     // fixed combine order: deterministic
    a0 += psum[(size_t)(s * NCLS + c) * DIM + tid];
    a1 += psum[(size_t)(s * NCLS + c) * DIM + 256 + tid];
    total += pcnt[s * NCLS + c];
  }
  const float inv = 1.0f / ((float)total + 1e-8f);   // counts + EPS
  const float p0 = a0 * inv, p1 = a1 * inv;
  {
    const int d = tid;
    const int ck = d >> 5, uL = (d >> 3) & 3, e = d & 7;
    protoI[(size_t)ck * CHUS + c * 32 + (uL ^ sw) * 8 + e] = (unsigned short)bf16s(p0);
  }
  {
    const int d = tid + 256;
    const int ck = d >> 5, uL = (d >> 3) & 3, e = d & 7;
    protoI[(size_t)ck * CHUS + c * 32 + (uL ^ sw) * 8 + e] = (unsigned short)bf16s(p1);
  }

  red[tid] = p0 * p0 + p1 * p1;
  __syncthreads();
  for (int st = 128; st > 0; st >>= 1) {
    if (tid < st) red[tid] += red[tid + st];
    __syncthreads();
  }
  if (tid == 0) p2out[c] = red[0];
}

// ---------------- Kernel 2: depth-3 gload_lds-B MFMA GEMM + argmin + loss ------
// R10 structure with deeper pipeline: B triple-buffered (BGLD t+2 issued at
// phase t -> 2 phases of flight; steady barrier vmcnt(8)); A triple register
// sets (issued t+3, stored t+2 -> 2 phases of flight).
__global__ __launch_bounds__(256) void k_score(
    const float* __restrict__ feat, const int* __restrict__ labels,
    const unsigned short* __restrict__ protoI, const float* __restrict__ p2,
    float* __restrict__ partials)
{
  __shared__ __align__(16) unsigned short As[2][BM * BK];    // 8 KiB
  __shared__ __align__(1024) unsigned short Bs[3][CHUS];     // 48 KiB
  __shared__ float f2s[BM][4];
  __shared__ float rd_d[2][BM];
  __shared__ int   rd_c[2][BM];
  __shared__ float rd_p[2][BM];

  const int tid = threadIdx.x;
  const int lane = tid & 63;
  const int w = tid >> 6;
  const int wm = w >> 1, wn = w & 1;
  const int lr = lane & 15;
  const int kg = lane >> 4;
  const int blockRow = blockIdx.x * BM;

  // A staging: 4 threads/row, 8 floats each; XOR-swizzled 16B units
  const int arow = tid >> 2, apart = tid & 3;
  const float* agp = feat + (size_t)(blockRow + arow) * DIM + apart * 8;
  const int aoff = arow * BK + ((apart ^ (arow & 3)) * 8);

  float f2part = 0.f;

  f32x4 acc0[NTW], acc1[NTW];
  #pragma unroll
  for (int n = 0; n < NTW; ++n) {
    acc0[n] = f32x4{0.f, 0.f, 0.f, 0.f};
    acc1[n] = f32x4{0.f, 0.f, 0.f, 0.f};
  }

  const int r0v = wm * 32 + lr;
  const int r1v = r0v + 16;
  const int ar0 = r0v * BK + ((kg ^ (r0v & 3)) * 8);
  const int ar1 = r1v * BK + ((kg ^ (r1v & 3)) * 8);

#define ISSUE_A(T, S) do {                                                      \
    const float* ag_ = agp + (T) * BK;                                          \
    S##0 = *(const f32x4*)(ag_);                                                \
    S##1 = *(const f32x4*)(ag_ + 4);                                            \
  } while (0)

#define STOREA(NB, S) do {                                                      \
    f2part += sumsq(S##0) + sumsq(S##1);                                        \
    *(bf16x8*)&As[NB][aoff] = pack8(S##0, S##1);                                \
  } while (0)

#define BGLD(T, NB) do {                                                        \
    _Pragma("unroll")                                                           \
    for (int i_ = 0; i_ < 4; ++i_) {                                            \
      const int j_ = w * 4 + i_;                                                \
      const unsigned short* g_ = protoI + (size_t)(T) * CHUS + j_ * 512 + lane * 8; \
      unsigned short* l_ = &Bs[NB][j_ * 512];                                   \
      __builtin_amdgcn_global_load_lds(                                         \
          (const __attribute__((address_space(1))) void*)g_,                    \
          (__attribute__((address_space(3))) void*)l_, 16, 0, 0);               \
    }                                                                           \
  } while (0)

#define COMPUTE(CURA, CURB) do {                                                \
    const bf16x8 Af0 = *(const bf16x8*)&As[CURA][ar0];                          \
    const bf16x8 Af1 = *(const bf16x8*)&As[CURA][ar1];                          \
    _Pragma("unroll")                                                           \
    for (int n = 0; n < NTW; ++n) {                                             \
      const int row_ = wn * 112 + n * 16 + lr;                                  \
      const bf16x8 Bf = *(const bf16x8*)&Bs[CURB][row_ * 32 + ((kg ^ ((row_ >> 1) & 3)) * 8)]; \
      acc0[n] = __builtin_amdgcn_mfma_f32_16x16x32_bf16(Af0, Bf, acc0[n], 0, 0, 0); \
      acc1[n] = __builtin_amdgcn_mfma_f32_16x16x32_bf16(Af1, Bf, acc1[n], 0, 0, 0); \
    }                                                                           \
  } while (0)

#define BAR_VM8() do {                                                          \
    asm volatile("s_waitcnt vmcnt(8)" ::: "memory");                            \
    asm volatile("s_waitcnt lgkmcnt(0)" ::: "memory");                          \
    __builtin_amdgcn_s_barrier();                                               \
  } while (0)

#define BAR_VM6() do {                                                          \
    asm volatile("s_waitcnt vmcnt(6)" ::: "memory");                            \
    asm volatile("s_waitcnt lgkmcnt(0)" ::: "memory");                          \
    __builtin_amdgcn_s_barrier();                                               \
  } while (0)

#define BAR_VM0() do {                                                          \
    asm volatile("s_waitcnt vmcnt(0)" ::: "memory");                            \
    asm volatile("s_waitcnt lgkmcnt(0)" ::: "memory");                          \
    __builtin_amdgcn_s_barrier();                                               \
  } while (0)

  // 3 A register sets: chunk c uses set c%3
  f32x4 S0_0, S0_1, S1_0, S1_1, S2_0, S2_1;

  // ---- prologue: A chunks 0,1,2 + B chunks 0,1 in flight ----
  ISSUE_A(0, S0_);
  BGLD(0, 0);
  BGLD(1, 1);
  __builtin_amdgcn_sched_barrier(0);
  ISSUE_A(1, S1_);
  ISSUE_A(2, S2_);
  STOREA(0, S0_);                 // waits S0 only (older than BGLDs? no: S0
                                  // issued first; its wait leaves B0/B1 flying)
  BAR_VM8();                      // drains B0 (8 newer: B1:4, S1:2, S2:2)

  // ---- 16 chunk phases; chunk t: A buf t&1, A set t%3, B buf t%3 ----
  #pragma unroll
  for (int t = 0; t < KIT; ++t) {
    if (t + 1 < KIT) {            // store A for chunk t+1 (issued 2 phases ago)
      if (((t + 1) % 3) == 0) STOREA((t + 1) & 1, S0_);
      else if (((t + 1) % 3) == 1) STOREA((t + 1) & 1, S1_);
      else STOREA((t + 1) & 1, S2_);
    }
    if (t + 2 < KIT) BGLD(t + 2, (t + 2) % 3);
    __builtin_amdgcn_sched_barrier(0);
    if (t + 3 < KIT) {            // issue A for chunk t+3 into set t%3 (free)
      if ((t % 3) == 0) ISSUE_A(t + 3, S0_);
      else if ((t % 3) == 1) ISSUE_A(t + 3, S1_);
      else ISSUE_A(t + 3, S2_);
    }
    COMPUTE(t & 1, t % 3);
    if (t + 1 < KIT) {
      if (t <= KIT - 4) BAR_VM8();        // steady: A(t+2):2 B(t+2):4 A(t+3):2
      else if (t == KIT - 3) BAR_VM6();   // A(15):2 B(15):4
      else BAR_VM0();                     // t = KIT-2: drain everything
    }
  }
#undef ISSUE_A
#undef STOREA
#undef BGLD
#undef COMPUTE
#undef BAR_VM8
#undef BAR_VM6
#undef BAR_VM0

  // exact per-row-part f2 (fixed combine order)
  f2s[arow][apart] = f2part;
  __syncthreads();

  float p2v[NTW];
  #pragma unroll
  for (int n = 0; n < NTW; ++n) p2v[n] = p2[wn * 112 + n * 16 + lr];

  #pragma unroll
  for (int m = 0; m < 2; ++m) {
    #pragma unroll
    for (int r = 0; r < 4; ++r) {
      const int srow = kg * 4 + r;                    // C/D row within 16-tile
      const int lrow = wm * 32 + m * 16 + srow;       // block-local sample row
      const float f2v = (f2s[lrow][0] + f2s[lrow][1]) + (f2s[lrow][2] + f2s[lrow][3]);
      const int lab = labels[blockRow + lrow];
      float bestd = 1e38f; int bestc = 1 << 30;
      float posd = -1.f;
      #pragma unroll
      for (int n = 0; n < NTW; ++n) {
        const int cidx = wn * 112 + n * 16 + lr;      // C/D col = class
        const float sc = (m == 0) ? acc0[n][r] : acc1[n][r];
        const float d2 = fmaxf(f2v + p2v[n] - 2.0f * sc, 0.0f);
        if (cidx == lab) posd = d2;
        else if (cidx < NCLS &&
                 (d2 < bestd || (d2 == bestd && cidx < bestc))) { bestd = d2; bestc = cidx; }
      }
      #pragma unroll
      for (int sft = 1; sft < 16; sft <<= 1) {        // 16-lane group reduce
        const float od = __shfl_xor(bestd, sft);
        const int   oc = __shfl_xor(bestc, sft);
        const float op = __shfl_xor(posd, sft);
        if (od < bestd || (od == bestd && oc < bestc)) { bestd = od; bestc = oc; }
        posd = fmaxf(posd, op);
      }
      if (lr == 0) {
        rd_d[wn][lrow] = bestd; rd_c[wn][lrow] = bestc; rd_p[wn][lrow] = posd;
      }
    }
  }
  __syncthreads();

  if (tid < BM) {                                     // combine + per-block loss
    const float d0 = rd_d[0][tid], d1 = rd_d[1][tid];
    const int   c0 = rd_c[0][tid], c1 = rd_c[1][tid];
    float bestd;
    if (d1 < d0 || (d1 == d0 && c1 < c0)) bestd = d1;
    else                                  bestd = d0;
    const float posd = fmaxf(rd_p[0][tid], rd_p[1][tid]);
    const float dap = posd, dan = bestd;
    const float dapn = dap / (dap + dan + 1e-8f);
    const float dann = dan / (dapn + dan + 1e-8f);    // sequential normalization
    float v = fmaxf(0.f, 1.5f * dapn - 0.8f * dann + 0.6f);
    #pragma unroll
    for (int sft = 1; sft < 64; sft <<= 1) v += __shfl_xor(v, sft);
    if (tid == 0) partials[blockIdx.x] = v;
  }
}

// ---------------- Kernel 3: deterministic final reduce (512 partials) ----------
__global__ __launch_bounds__(256) void k_finish(const float* __restrict__ partials,
                                                float* __restrict__ out)
{
  __shared__ float red[256];
  const int tid = threadIdx.x;
  red[tid] = partials[tid] + partials[tid + 256];
  __syncthreads();
  for (int st = 128; st > 0; st >>= 1) {
    if (tid < st) red[tid] += red[tid + st];
    __syncthreads();
  }
  if (tid == 0) out[0] = fabsf(0.2f * (red[0] / (float)NSAMP));
}

extern "C" void kernel_launch(void* const* d_in, const int* in_sizes, int n_in,
                              void* d_out, int out_size, void* d_ws, size_t ws_size,
                              hipStream_t stream) {
  const float* feat = (const float*)d_in[0];
  const int* labels = (const int*)d_in[1];
  float* out = (float*)d_out;

  char* ws = (char*)d_ws;
  unsigned short* protoI = (unsigned short*)ws;          // 16*8192*2 = 262144 B
  float* p2 = (float*)(ws + 262144);                     // 224 floats (pad 1K)
  float* partials = (float*)(ws + 263168);               // 512 floats
  float* psum = (float*)(ws + 266240);                   // 8*200*512*4 = 3276800 B
  int* pcnt = (int*)(ws + 266240 + 3276800);             // 1600 ints

  k_psum<<<NSEG * NCLS, 512, 0, stream>>>(feat, labels, psum, pcnt);
  k_pcomb<<<NPADP, 256, 0, stream>>>(psum, pcnt, protoI, p2);
  k_score<<<512, 256, 0, stream>>>(feat, labels, protoI, p2, partials);
  k_finish<<<1, 256, 0, stream>>>(partials, out);
}